// Round 2
// baseline (1671.656 us; speedup 1.0000x reference)
//
#include <hip/hip_runtime.h>
#include <hip/hip_bf16.h>
#include <math.h>

#define BB 4
#define SS 2048
#define EE 1024
#define HH 8
#define DD 128
#define BSR (BB*SS)      // 8192 rows
#define HD  (HH*DD)      // 1024
#define LNEPS 1e-5f
#define LOG2E 1.4426950408889634f

// ---- pipeline geometry ----
#define NCHUNK 16
#define CHS    128            // timesteps per chunk
#define TPC    160            // tickets per chunk: 32 A + 32 B + 32 C + 32 D + 32 E
#define NTICK  (NCHUNK*TPC)
#define NWORKER 512
#define SLOTF  (BB*CHS*1024) // floats per wsum slot (512 rows x 1024)

typedef __attribute__((ext_vector_type(8))) short bf16x8;
typedef __attribute__((ext_vector_type(4))) float f32x4;

__device__ __forceinline__ ushort f2bf(float f) {
    union { float f; unsigned u; } c{f};
    unsigned r = c.u + 0x7fff + ((c.u >> 16) & 1);   // RNE
    return (ushort)(r >> 16);
}
__device__ __forceinline__ float bf2f(ushort b) {
    union { unsigned u; float f; } c{(unsigned)b << 16};
    return c.f;
}

typedef __attribute__((address_space(1))) const unsigned int GUI;
typedef __attribute__((address_space(3))) unsigned int LUI;
__device__ __forceinline__ void gl_lds16(const ushort* g, ushort* l) {
    __builtin_amdgcn_global_load_lds((GUI*)g, (LUI*)l, 16, 0, 0);
}

// ------------------------------------------------- DPP wave reduction ------
__device__ __forceinline__ float dpp_add(float x, const int ctrl) {
    int y;
    switch (ctrl) {
        case 0x111: y = __builtin_amdgcn_update_dpp(0, __float_as_int(x), 0x111, 0xf, 0xf, true); break;
        case 0x112: y = __builtin_amdgcn_update_dpp(0, __float_as_int(x), 0x112, 0xf, 0xf, true); break;
        case 0x114: y = __builtin_amdgcn_update_dpp(0, __float_as_int(x), 0x114, 0xf, 0xf, true); break;
        case 0x118: y = __builtin_amdgcn_update_dpp(0, __float_as_int(x), 0x118, 0xf, 0xf, true); break;
        case 0x142: y = __builtin_amdgcn_update_dpp(0, __float_as_int(x), 0x142, 0xf, 0xf, true); break;
        default:    y = __builtin_amdgcn_update_dpp(0, __float_as_int(x), 0x143, 0xf, 0xf, true); break;
    }
    return x + __int_as_float(y);
}

__device__ __forceinline__ float wave_sum64(float x) {
    x = dpp_add(x, 0x111);
    x = dpp_add(x, 0x112);
    x = dpp_add(x, 0x114);
    x = dpp_add(x, 0x118);
    x = dpp_add(x, 0x142);
    x = dpp_add(x, 0x143);
    return __int_as_float(__builtin_amdgcn_readlane(__float_as_int(x), 63));
}

// ------------------------------------------------ flag sync primitives -----
__device__ __forceinline__ void wait_ge(unsigned* f, unsigned tgt) {
    if (threadIdx.x == 0) {
        while (__hip_atomic_load(f, __ATOMIC_ACQUIRE, __HIP_MEMORY_SCOPE_AGENT) < tgt)
            __builtin_amdgcn_s_sleep(16);
    }
    __syncthreads();
}
__device__ __forceinline__ void done_inc(unsigned* f) {
    __threadfence();
    __syncthreads();
    if (threadIdx.x == 0)
        __hip_atomic_fetch_add(f, 1u, __ATOMIC_RELEASE, __HIP_MEMORY_SCOPE_AGENT);
}

// --------------------------------------- fp32 -> bf16 hi/lo split convert --
__global__ __launch_bounds__(256)
void convx2_k(const float* __restrict__ x,
              ushort* __restrict__ hi, ushort* __restrict__ lo)
{
    const size_t idx = ((size_t)blockIdx.x * 256 + threadIdx.x) * 4;
    const float4 v = *(const float4*)(x + idx);
    ushort4 oh, ol;
    oh.x = f2bf(v.x); ol.x = f2bf(v.x - bf2f(oh.x));
    oh.y = f2bf(v.y); ol.y = f2bf(v.y - bf2f(oh.y));
    oh.z = f2bf(v.z); ol.z = f2bf(v.z - bf2f(oh.z));
    oh.w = f2bf(v.w); ol.w = f2bf(v.w - bf2f(oh.w));
    *(ushort4*)(hi + idx) = oh;
    *(ushort4*)(lo + idx) = ol;
}

// ---------------------- merged weight prep (transposes + diagonals + q/c) --
__global__ __launch_bounds__(256)
void prepall_k(const float* __restrict__ W_ez,
               ushort* __restrict__ Wth, ushort* __restrict__ Wtl,
               const float* __restrict__ W2, ushort* __restrict__ W2t,
               const float* __restrict__ W1, ushort* __restrict__ W1t,
               const float* __restrict__ w_att, const float* __restrict__ b2,
               const float* __restrict__ b_att,
               const float* __restrict__ Uh, const float* __restrict__ Uz,
               const float* __restrict__ Os,
               float* __restrict__ q, float* __restrict__ c,
               float* __restrict__ uh_d, float* __restrict__ uz_d,
               float* __restrict__ os_d, unsigned* __restrict__ flags)
{
    __shared__ float tile[32][33];
    const int blk = blockIdx.x;
    if (blk == 2434) {                      // zero sync flags for the pipeline
        if (threadIdx.x < 128) flags[threadIdx.x] = 0;
        return;
    }
    const int tx = threadIdx.x & 31, ty = threadIdx.x >> 5;   // ty 0..7
    if (blk < 1024) {
        const int k0 = (blk >> 5) * 32, n0 = (blk & 31) * 32;
        #pragma unroll
        for (int i = 0; i < 4; ++i)
            tile[ty + i*8][tx] = W_ez[(size_t)(k0 + ty + i*8) * 1024 + n0 + tx];
        __syncthreads();
        #pragma unroll
        for (int i = 0; i < 4; ++i) {
            const float v = tile[tx][ty + i*8];
            const ushort h = f2bf(v);
            Wth[(size_t)(n0 + ty + i*8) * 1024 + k0 + tx] = h;
            Wtl[(size_t)(n0 + ty + i*8) * 1024 + k0 + tx] = f2bf(v - bf2f(h));
        }
    } else if (blk < 2048) {
        const int b2i = blk - 1024;
        const int k0 = (b2i >> 5) * 32, n0 = (b2i & 31) * 32;
        #pragma unroll
        for (int i = 0; i < 4; ++i)
            tile[ty + i*8][tx] = W2[(size_t)(k0 + ty + i*8) * 1024 + n0 + tx];
        __syncthreads();
        #pragma unroll
        for (int i = 0; i < 4; ++i)
            W2t[(size_t)(n0 + ty + i*8) * 1024 + k0 + tx] = f2bf(tile[tx][ty + i*8]);
    } else if (blk < 2176) {
        const int idx = blk - 2048;
        const int hh = idx >> 4;
        const int k0 = (idx & 3) * 32, n0 = ((idx >> 2) & 3) * 32;
        const float* Wb = W1 + (size_t)hh * DD * DD;
        ushort*      Wtb = W1t + (size_t)hh * DD * DD;
        #pragma unroll
        for (int i = 0; i < 4; ++i)
            tile[ty + i*8][tx] = Wb[(size_t)(k0 + ty + i*8) * DD + n0 + tx];
        __syncthreads();
        #pragma unroll
        for (int i = 0; i < 4; ++i)
            Wtb[(size_t)(n0 + ty + i*8) * DD + k0 + tx] = f2bf(tile[tx][ty + i*8]);
    } else {
        const int gid  = (blk - 2176) * 256 + threadIdx.x;
        const int wave = gid >> 6, lane = gid & 63;
        if (wave < HD) {
            const float* wp = W2 + (size_t)wave * EE;
            float p = 0.f;
            for (int e = lane; e < EE; e += 64) p = fmaf(wp[e], w_att[e], p);
            #pragma unroll
            for (int off = 32; off > 0; off >>= 1) p += __shfl_xor(p, off, 64);
            if (lane == 0) {
                q[wave] = p;
                const int h = wave >> 7, d = wave & 127;
                uh_d[wave] = Uh[(size_t)h*DD*DD + (size_t)d*DD + d];
                uz_d[wave] = Uz[(size_t)h*DD*DD + (size_t)d*DD + d];
                os_d[wave] = Os[(size_t)h*DD*DD + (size_t)d*DD + d];
            }
        } else if (wave < HD + HH) {
            const int h = wave - HD;
            const float* bp = b2 + (size_t)h * EE;
            float p = 0.f;
            for (int e = lane; e < EE; e += 64) p = fmaf(bp[e], w_att[e], p);
            #pragma unroll
            for (int off = 32; off > 0; off >>= 1) p += __shfl_xor(p, off, 64);
            if (lane == 0) c[h] = p + b_att[0];
        }
    }
}

// ----------------------------------- split-bf16 MFMA GEMM (z, fp32-class) --
__global__ __launch_bounds__(256)
void gemm_mfma_hp(const ushort* __restrict__ Ah, const ushort* __restrict__ Al,
                  const ushort* __restrict__ Bh, const ushort* __restrict__ Bl,
                  float* __restrict__ C, const float* __restrict__ bias)
{
    __shared__ ushort AsmH[128*32], AsmL[128*32];
    __shared__ ushort BsmH[128*32], BsmL[128*32];
    const int t = threadIdx.x, lane = t & 63, w = t >> 6;
    const int wr = w >> 1, wc = w & 1;
    const int row0 = blockIdx.x * 128, col0 = blockIdx.y * 128;

    const int lr = lane >> 2;
    const int lc = (lane & 3) ^ (lr & 3);
    const size_t aoff0 = (size_t)(row0 +      w*16 + lr) * 1024 + lc*8;
    const size_t aoff1 = (size_t)(row0 + 64 + w*16 + lr) * 1024 + lc*8;
    const size_t boff0 = (size_t)(col0 +      w*16 + lr) * 1024 + lc*8;
    const size_t boff1 = (size_t)(col0 + 64 + w*16 + lr) * 1024 + lc*8;
    ushort* AH0 = AsmH + (     w*16) * 32;  ushort* AH1 = AsmH + (64 + w*16) * 32;
    ushort* AL0 = AsmL + (     w*16) * 32;  ushort* AL1 = AsmL + (64 + w*16) * 32;
    ushort* BH0 = BsmH + (     w*16) * 32;  ushort* BH1 = BsmH + (64 + w*16) * 32;
    ushort* BL0 = BsmL + (     w*16) * 32;  ushort* BL1 = BsmL + (64 + w*16) * 32;

    f32x4 acc[4][4];
    #pragma unroll
    for (int i = 0; i < 4; ++i)
        #pragma unroll
        for (int j = 0; j < 4; ++j) acc[i][j] = (f32x4){0.f,0.f,0.f,0.f};

    const int quad = lane >> 4;
    const int fr   = lane & 15;
    const int fchk = (quad ^ (lane & 3)) * 8;

    for (int k0 = 0; k0 < 1024; k0 += 32) {
        __syncthreads();
        gl_lds16(Ah + aoff0 + k0, AH0);
        gl_lds16(Ah + aoff1 + k0, AH1);
        gl_lds16(Bh + boff0 + k0, BH0);
        gl_lds16(Bh + boff1 + k0, BH1);
        gl_lds16(Al + aoff0 + k0, AL0);
        gl_lds16(Al + aoff1 + k0, AL1);
        gl_lds16(Bl + boff0 + k0, BL0);
        gl_lds16(Bl + boff1 + k0, BL1);
        __syncthreads();

        bf16x8 afh[4], afl[4], bfh[4], bfl[4];
        #pragma unroll
        for (int i = 0; i < 4; ++i) {
            const int ra = (wr*64 + i*16 + fr) * 32 + fchk;
            afh[i] = *(const bf16x8*)(AsmH + ra);
            afl[i] = *(const bf16x8*)(AsmL + ra);
            const int rb = (wc*64 + i*16 + fr) * 32 + fchk;
            bfh[i] = *(const bf16x8*)(BsmH + rb);
            bfl[i] = *(const bf16x8*)(BsmL + rb);
        }
        #pragma unroll
        for (int i = 0; i < 4; ++i)
            #pragma unroll
            for (int j = 0; j < 4; ++j) {
                acc[i][j] = __builtin_amdgcn_mfma_f32_16x16x32_bf16(
                    afh[i], bfl[j], acc[i][j], 0, 0, 0);
                acc[i][j] = __builtin_amdgcn_mfma_f32_16x16x32_bf16(
                    afl[i], bfh[j], acc[i][j], 0, 0, 0);
                acc[i][j] = __builtin_amdgcn_mfma_f32_16x16x32_bf16(
                    afh[i], bfh[j], acc[i][j], 0, 0, 0);
            }
    }

    float colv[4];
    #pragma unroll
    for (int tj = 0; tj < 4; ++tj)
        colv[tj] = bias[col0 + wc*64 + tj*16 + fr];
    #pragma unroll
    for (int ti = 0; ti < 4; ++ti)
        #pragma unroll
        for (int i = 0; i < 4; ++i) {
            const int row = row0 + wr*64 + ti*16 + quad*4 + i;
            #pragma unroll
            for (int tj = 0; tj < 4; ++tj) {
                const int col = col0 + wc*64 + tj*16 + fr;
                C[(size_t)row*1024 + col] = tanhf(acc[ti][tj][i] + colv[tj]);
            }
        }
}

// ===========================================================================
// Fused producer-consumer pipeline:
//   blocks [0,32)          : scan chains (b,h); release F_scan[c] per 128 steps
//   blocks [32, 32+NWORKER): persistent workers, global in-order ticket queue
//     per chunk c: 32x headln (A) -> 32x gemm_h1 (B) -> 32x softscale (C)
//                  -> 32x gemm_mfma (D) -> 32x finalln (E)
// Tickets are claimed in topological order => deadlock-free for any residency.
// wsum lives in 8 rotating slots (D[c] also gated on E[c-8]).
// gb ALIASES stb (same [bs][1024] ushort layout): stage C[c] overwrites the
// state rows of chunk c, whose only consumer A[c] is transitively complete.
// z (bufA) is READ-ONLY for the whole pipeline (R1 bug: gb aliased z with a
// 2x byte-offset mismatch and clobbered future scan inputs).
// flags: [0]=ticket [1..16]=F_scan [17..32]=F_A [33..48]=F_B [49..64]=F_C
//        [65..80]=F_D [81..96]=F_E
// ===========================================================================
__global__ __launch_bounds__(256)
void pipeline_k(const float* __restrict__ z,
                const float* __restrict__ uh_d, const float* __restrict__ uz_d,
                const float* __restrict__ b_u,
                const float* __restrict__ lns_g, const float* __restrict__ lns_b,
                ushort* stb,                          // aliases gb! no restrict
                const float* __restrict__ os_d,
                const float* __restrict__ ffg, const float* __restrict__ ffb,
                ushort* __restrict__ hlnb,
                const ushort* __restrict__ W1t, const float* __restrict__ ff_b1,
                const float* __restrict__ qv, const float* __restrict__ cv,
                ushort* __restrict__ h1b, float* __restrict__ logits,
                ushort* gb,                           // aliases stb! no restrict
                float* __restrict__ scores,
                const ushort* __restrict__ W2t, const float* __restrict__ ff_b2,
                float* __restrict__ wslots,
                const float* __restrict__ lno_g, const float* __restrict__ lno_b,
                float* __restrict__ out,
                unsigned* __restrict__ flags)
{
    // ------------------------------------------------------- scan role -----
    if (blockIdx.x < 32) {
        if (threadIdx.x >= 64) return;
        const int bh = blockIdx.x;
        const int b = bh >> 3, h = bh & 7;
        const int l = threadIdx.x;
        const int d0 = 2*l, d1 = d0 + 1;

        const float uhn0 = -uh_d[h*DD+d0] * LOG2E, uhn1 = -uh_d[h*DD+d1] * LOG2E;
        const float uzn0 = -uz_d[h*DD+d0] * LOG2E, uzn1 = -uz_d[h*DD+d1] * LOG2E;
        const float bun0 = -b_u [h*DD+d0] * LOG2E, bun1 = -b_u [h*DD+d1] * LOG2E;
        const float g0  = lns_g[d0], g1 = lns_g[d1];
        const float be0 = lns_b[d0], be1 = lns_b[d1];
        const float A0 = g0 * uhn0, A1 = g1 * uhn1;
        const float bunB0 = fmaf(be0, uhn0, bun0);
        const float bunB1 = fmaf(be1, uhn1, bun1);

        const float* zp = z + ((size_t)b * SS * HH + h) * DD + d0;
        unsigned* op = (unsigned*)(stb + (size_t)b * SS * HD + h * DD) + l;

        const int CH = 8;
        float2 zc[CH], zn[CH];
        float pb0[CH], pb1[CH];
        #pragma unroll
        for (int i = 0; i < CH; ++i) zc[i] = *(const float2*)(zp + (size_t)i*HD);
        #pragma unroll
        for (int i = 0; i < CH; ++i) {
            pb0[i] = fmaf(zc[i].x, uzn0, bunB0);
            pb1[i] = fmaf(zc[i].y, uzn1, bunB1);
        }

        float r_c, wp0, wp1, W0, W1, dv0, dv1;

#define PACK_STORE(HP0, HP1, OFF) do {                                       \
            const unsigned pu0 = __float_as_uint(HP0) + 0x8000u;             \
            const unsigned pu1 = __float_as_uint(HP1) + 0x8000u;             \
            op[(size_t)(OFF) * (HD/2)] =                                     \
                __builtin_amdgcn_perm(pu1, pu0, 0x07060302u);                \
        } while (0)

#define SCAN_STEP(ZX, ZY, PB0v, PB1v, ZNX, ZNY, OFF) do {                    \
            const float t0 = fmaf(r_c, W0, (PB0v));                          \
            const float t1 = fmaf(r_c, W1, (PB1v));                          \
            const float e0 = __builtin_amdgcn_exp2f(t0);                     \
            const float e1 = __builtin_amdgcn_exp2f(t1);                     \
            const float u0 = __builtin_amdgcn_rcpf(1.f + e0);                \
            const float u1 = __builtin_amdgcn_rcpf(1.f + e1);                \
            const float hn0 = fmaf(u0, dv0, (ZX));                           \
            const float hn1 = fmaf(u1, dv1, (ZY));                           \
            const float s1 = wave_sum64(hn0 + hn1);                          \
            const float s2 = wave_sum64(fmaf(hn0, hn0, hn1*hn1));            \
            const float m   = s1 * (1.f/128.f);                              \
            const float var = fmaf(s2, 1.f/128.f, -m*m);                     \
            r_c = __builtin_amdgcn_rsqf(var + LNEPS);                        \
            wp0 = hn0 - m; wp1 = hn1 - m;                                    \
            W0 = wp0 * A0; W1 = wp1 * A1;                                    \
            const float hp0 = fmaf(wp0, r_c * g0, be0);                      \
            const float hp1 = fmaf(wp1, r_c * g1, be1);                      \
            PACK_STORE(hp0, hp1, OFF);                                       \
            dv0 = hp0 - (ZNX); dv1 = hp1 - (ZNY);                            \
        } while (0)

        // ---- peel step 0 (h_prev = 0) ----
        {
            const float z0 = zc[0].x, z1 = zc[0].y;
            const float t0 = fmaf(z0, uzn0, bun0);
            const float t1 = fmaf(z1, uzn1, bun1);
            const float e0 = __builtin_amdgcn_exp2f(t0);
            const float e1 = __builtin_amdgcn_exp2f(t1);
            const float u0 = __builtin_amdgcn_rcpf(1.f + e0);
            const float u1 = __builtin_amdgcn_rcpf(1.f + e1);
            const float hn0 = fmaf(u0, -z0, z0);
            const float hn1 = fmaf(u1, -z1, z1);
            const float s1 = wave_sum64(hn0 + hn1);
            const float s2 = wave_sum64(fmaf(hn0, hn0, hn1*hn1));
            const float m   = s1 * (1.f/128.f);
            const float var = fmaf(s2, 1.f/128.f, -m*m);
            r_c = __builtin_amdgcn_rsqf(var + LNEPS);
            wp0 = hn0 - m; wp1 = hn1 - m;
            W0 = wp0 * A0; W1 = wp1 * A1;
            const float hp0 = fmaf(wp0, r_c * g0, be0);
            const float hp1 = fmaf(wp1, r_c * g1, be1);
            PACK_STORE(hp0, hp1, 0);
            dv0 = hp0 - zc[1].x; dv1 = hp1 - zc[1].y;
        }

        // ---- rest of chunk 0 (steps 1..7) ----
        #pragma unroll
        for (int i = 0; i < CH; ++i)
            zn[i] = *(const float2*)(zp + (size_t)(CH+i)*HD);
        #pragma unroll
        for (int i = 1; i < CH; ++i) {
            const float znx = (i+1 < CH) ? zc[i+1].x : zn[0].x;
            const float zny = (i+1 < CH) ? zc[i+1].y : zn[0].y;
            SCAN_STEP(zc[i].x, zc[i].y, pb0[i], pb1[i], znx, zny, i);
        }
        #pragma unroll
        for (int i = 0; i < CH; ++i) {
            zc[i] = zn[i];
            pb0[i] = fmaf(zn[i].x, uzn0, bunB0);
            pb1[i] = fmaf(zn[i].y, uzn1, bunB1);
        }

        // ---- chunks of 8 steps, flag every CHS=128 steps ----
        for (int s0 = CH; s0 < SS; s0 += CH) {
            if (s0 + CH < SS) {
                #pragma unroll
                for (int i = 0; i < CH; ++i)
                    zn[i] = *(const float2*)(zp + (size_t)(s0+CH+i)*HD);
            } else {
                #pragma unroll
                for (int i = 0; i < CH; ++i) zn[i] = make_float2(0.f, 0.f);
            }
            #pragma unroll
            for (int i = 0; i < CH; ++i) {
                const float znx = (i+1 < CH) ? zc[i+1].x : zn[0].x;
                const float zny = (i+1 < CH) ? zc[i+1].y : zn[0].y;
                SCAN_STEP(zc[i].x, zc[i].y, pb0[i], pb1[i], znx, zny, s0 + i);
            }
            #pragma unroll
            for (int i = 0; i < CH; ++i) {
                zc[i] = zn[i];
                pb0[i] = fmaf(zn[i].x, uzn0, bunB0);
                pb1[i] = fmaf(zn[i].y, uzn1, bunB1);
            }
            if ((s0 & (CHS-1)) == CHS - CH) {       // finished chunk s0>>7
                __threadfence();
                if (threadIdx.x == 0)
                    __hip_atomic_fetch_add(&flags[1 + (s0 >> 7)], 1u,
                                           __ATOMIC_RELEASE, __HIP_MEMORY_SCOPE_AGENT);
            }
        }
#undef SCAN_STEP
#undef PACK_STORE
        return;
    }

    // ----------------------------------------------------- worker role -----
    __shared__ ushort Asm[128*32];
    __shared__ ushort Bsm[128*32];
    __shared__ float lpart[128][2];
    __shared__ float r1s[4], r2s[4];
    __shared__ unsigned s_tk;
    const int tid = threadIdx.x;

    for (;;) {
        __syncthreads();
        if (tid == 0) s_tk = atomicAdd(&flags[0], 1u);
        __syncthreads();
        const unsigned tk = s_tk;
        if (tk >= NTICK) return;
        const int c  = (int)(tk / TPC);
        const int r  = (int)(tk % TPC);

        if (r < 32) {
            // ----------------- stage A: headln (diag scale + per-head LN) --
            wait_ge(&flags[1 + c], 32);
            const int b = r >> 3, i8 = r & 7;
            const int bs0 = b*SS + c*CHS + i8*16;
            const int l = tid & 63;
            const int d0 = 2*l, d1 = d0 + 1;
            const unsigned* st_u = (const unsigned*)stb;
            unsigned* hln_u = (unsigned*)hlnb;
            for (int it = 0; it < 32; ++it) {
                const int u  = it*4 + (tid >> 6);
                const int bs = bs0 + (u >> 3);
                const int h  = u & 7;
                const int row = bs*8 + h;
                const unsigned v = st_u[(size_t)row*64 + l];
                const float x0 = bf2f((ushort)(v & 0xffff)) * os_d[h*DD + d0];
                const float x1 = bf2f((ushort)(v >> 16))    * os_d[h*DD + d1];
                float s1 = x0 + x1;
                float s2 = fmaf(x0, x0, x1*x1);
                #pragma unroll
                for (int off = 32; off > 0; off >>= 1) {
                    s1 += __shfl_xor(s1, off, 64);
                    s2 += __shfl_xor(s2, off, 64);
                }
                const float m   = s1 * (1.f/128.f);
                const float var = fmaf(s2, 1.f/128.f, -m*m);
                const float rr  = rsqrtf(var + LNEPS);
                const float o0 = fmaf((x0 - m)*rr, ffg[h*DD + d0], ffb[h*DD + d0]);
                const float o1 = fmaf((x1 - m)*rr, ffg[h*DD + d1], ffb[h*DD + d1]);
                hln_u[(size_t)row*64 + l] = (unsigned)f2bf(o0) | ((unsigned)f2bf(o1) << 16);
            }
            done_inc(&flags[17 + c]);
        } else if (r < 64) {
            // ---------- stage B: h1 = gelu(hln@W1[h]+b1) + fused logits ----
            wait_ge(&flags[17 + c], 32);
            const int sub = r - 32;
            const int bb = sub >> 3, hh = sub & 7;
            const int row0 = bb*SS + c*CHS;
            const int lane = tid & 63, w = tid >> 6;
            const int wr = w >> 1, wc = w & 1;
            const int lr = lane >> 2;
            const int lc = (lane & 3) ^ (lr & 3);
            const ushort* Ag0 = hlnb + (size_t)(row0 +      w*16 + lr) * 1024 + hh*DD + lc*8;
            const ushort* Ag1 = hlnb + (size_t)(row0 + 64 + w*16 + lr) * 1024 + hh*DD + lc*8;
            const ushort* Bg0 = W1t + (size_t)hh*DD*DD + (     w*16 + lr) * DD + lc*8;
            const ushort* Bg1 = W1t + (size_t)hh*DD*DD + (64 + w*16 + lr) * DD + lc*8;
            ushort* Al0 = Asm + (     w*16) * 32;
            ushort* Al1 = Asm + (64 + w*16) * 32;
            ushort* Bl0 = Bsm + (     w*16) * 32;
            ushort* Bl1 = Bsm + (64 + w*16) * 32;

            f32x4 acc[4][4];
            #pragma unroll
            for (int i = 0; i < 4; ++i)
                #pragma unroll
                for (int j = 0; j < 4; ++j) acc[i][j] = (f32x4){0.f,0.f,0.f,0.f};

            const int quad = lane >> 4;
            const int fr   = lane & 15;
            const int fchk = (quad ^ (lane & 3)) * 8;

            for (int k0 = 0; k0 < 128; k0 += 32) {
                __syncthreads();
                gl_lds16(Ag0 + k0, Al0);
                gl_lds16(Ag1 + k0, Al1);
                gl_lds16(Bg0 + k0, Bl0);
                gl_lds16(Bg1 + k0, Bl1);
                __syncthreads();

                bf16x8 af[4], bf[4];
                #pragma unroll
                for (int i = 0; i < 4; ++i) {
                    af[i] = *(const bf16x8*)(Asm + (wr*64 + i*16 + fr)*32 + fchk);
                    bf[i] = *(const bf16x8*)(Bsm + (wc*64 + i*16 + fr)*32 + fchk);
                }
                #pragma unroll
                for (int i = 0; i < 4; ++i)
                    #pragma unroll
                    for (int j = 0; j < 4; ++j)
                        acc[i][j] = __builtin_amdgcn_mfma_f32_16x16x32_bf16(
                            af[i], bf[j], acc[i][j], 0, 0, 0);
            }

            float colv[4], qh[4];
            #pragma unroll
            for (int tj = 0; tj < 4; ++tj) {
                const int col = wc*64 + tj*16 + fr;
                colv[tj] = ff_b1[hh*DD + col];
                qh[tj]   = qv[hh*DD + col];
            }
            #pragma unroll
            for (int ti = 0; ti < 4; ++ti)
                #pragma unroll
                for (int i = 0; i < 4; ++i) {
                    const int row = row0 + wr*64 + ti*16 + quad*4 + i;
                    float p = 0.f;
                    #pragma unroll
                    for (int tj = 0; tj < 4; ++tj) {
                        const int col = wc*64 + tj*16 + fr;
                        float v = acc[ti][tj][i] + colv[tj];
                        v = 0.5f * v * (1.f + erff(v * 0.70710678118654752f));
                        h1b[(size_t)row*1024 + hh*DD + col] = f2bf(v);
                        p = fmaf(v, qh[tj], p);
                    }
                    p = dpp_add(p, 0x111);
                    p = dpp_add(p, 0x112);
                    p = dpp_add(p, 0x114);
                    p = dpp_add(p, 0x118);
                    if (fr == 15)
                        lpart[wr*64 + ti*16 + quad*4 + i][wc] = p;
                }
            __syncthreads();
            if (tid < 128)
                logits[(size_t)(row0 + tid)*HH + hh] = lpart[tid][0] + lpart[tid][1] + cv[hh];
            done_inc(&flags[33 + c]);
        } else if (r < 96) {
            // ------------- stage C: softmax over heads + scale h1 -> gb ----
            wait_ge(&flags[33 + c], 32);
            const int sub = r - 64;
            const int b = sub >> 3, i8 = sub & 7;
            const int bs0 = b*SS + c*CHS + i8*16;
            const int h = (tid >> 5) & 7;
            for (int it = 0; it < 16; ++it) {
                const int bs = bs0 + it;
                const size_t idx = (size_t)bs*1024 + (size_t)tid*4;
                float lv[8];
                float mx = -1e30f;
                #pragma unroll
                for (int i = 0; i < 8; ++i) { lv[i] = logits[bs*8 + i]; mx = fmaxf(mx, lv[i]); }
                float den = 0.f;
                #pragma unroll
                for (int i = 0; i < 8; ++i) den += __expf(lv[i] - mx);
                const float sc = __expf(lv[h] - mx) / den;
                const ushort4 v = *(const ushort4*)(h1b + idx);
                ushort4 o;
                o.x = f2bf(bf2f(v.x) * sc); o.y = f2bf(bf2f(v.y) * sc);
                o.z = f2bf(bf2f(v.z) * sc); o.w = f2bf(bf2f(v.w) * sc);
                *(ushort4*)(gb + idx) = o;
                if ((tid & 31) == 0) scores[bs*8 + h] = sc;
            }
            done_inc(&flags[49 + c]);
        } else if (r < 128) {
            // ---- stage D: weighted = g @ W2 + sum_h score*b2  -> wslot ----
            wait_ge(&flags[49 + c], 32);
            if (c >= 8) wait_ge(&flags[81 + c - 8], 32);   // slot (c&7) free
            const int sub = r - 96;
            const int bb = sub >> 3, cb = sub & 7;
            const int row0 = bb*SS + c*CHS, col0 = cb*128;
            float* wslot = wslots + (size_t)(c & 7) * SLOTF;
            const int lane = tid & 63, w = tid >> 6;
            const int wr = w >> 1, wc = w & 1;
            const int lr = lane >> 2;
            const int lc = (lane & 3) ^ (lr & 3);
            const ushort* Ag0 = gb  + (size_t)(row0 +      w*16 + lr) * 1024 + lc*8;
            const ushort* Ag1 = gb  + (size_t)(row0 + 64 + w*16 + lr) * 1024 + lc*8;
            const ushort* Bg0 = W2t + (size_t)(col0 +      w*16 + lr) * 1024 + lc*8;
            const ushort* Bg1 = W2t + (size_t)(col0 + 64 + w*16 + lr) * 1024 + lc*8;
            ushort* Al0 = Asm + (     w*16) * 32;
            ushort* Al1 = Asm + (64 + w*16) * 32;
            ushort* Bl0 = Bsm + (     w*16) * 32;
            ushort* Bl1 = Bsm + (64 + w*16) * 32;

            f32x4 acc[4][4];
            #pragma unroll
            for (int i = 0; i < 4; ++i)
                #pragma unroll
                for (int j = 0; j < 4; ++j) acc[i][j] = (f32x4){0.f,0.f,0.f,0.f};

            const int quad = lane >> 4;
            const int fr   = lane & 15;
            const int fchk = (quad ^ (lane & 3)) * 8;

            for (int k0 = 0; k0 < 1024; k0 += 32) {
                __syncthreads();
                gl_lds16(Ag0 + k0, Al0);
                gl_lds16(Ag1 + k0, Al1);
                gl_lds16(Bg0 + k0, Bl0);
                gl_lds16(Bg1 + k0, Bl1);
                __syncthreads();

                bf16x8 af[4], bf[4];
                #pragma unroll
                for (int i = 0; i < 4; ++i) {
                    af[i] = *(const bf16x8*)(Asm + (wr*64 + i*16 + fr)*32 + fchk);
                    bf[i] = *(const bf16x8*)(Bsm + (wc*64 + i*16 + fr)*32 + fchk);
                }
                #pragma unroll
                for (int i = 0; i < 4; ++i)
                    #pragma unroll
                    for (int j = 0; j < 4; ++j)
                        acc[i][j] = __builtin_amdgcn_mfma_f32_16x16x32_bf16(
                            af[i], bf[j], acc[i][j], 0, 0, 0);
            }

            float b2v[4][HH];
            #pragma unroll
            for (int tj = 0; tj < 4; ++tj) {
                const int col = col0 + wc*64 + tj*16 + fr;
                #pragma unroll
                for (int h = 0; h < HH; ++h) b2v[tj][h] = ff_b2[(size_t)h*EE + col];
            }
            #pragma unroll
            for (int ti = 0; ti < 4; ++ti)
                #pragma unroll
                for (int i = 0; i < 4; ++i) {
                    const int row  = row0 + wr*64 + ti*16 + quad*4 + i;
                    const int lrow = bb*128 + wr*64 + ti*16 + quad*4 + i;
                    float sc[HH];
                    #pragma unroll
                    for (int h = 0; h < HH; ++h) sc[h] = scores[row*HH + h];
                    #pragma unroll
                    for (int tj = 0; tj < 4; ++tj) {
                        const int col = col0 + wc*64 + tj*16 + fr;
                        float bbv = 0.f;
                        #pragma unroll
                        for (int h = 0; h < HH; ++h) bbv = fmaf(sc[h], b2v[tj][h], bbv);
                        wslot[(size_t)lrow*1024 + col] = acc[ti][tj][i] + bbv;
                    }
                }
            done_inc(&flags[65 + c]);
        } else {
            // ----------------------- stage E: final LayerNorm -> out -------
            wait_ge(&flags[65 + c], 32);
            const int sub = r - 128;
            const int b = sub >> 3, i8 = sub & 7;
            const float* wslot = wslots + (size_t)(c & 7) * SLOTF;
            const float4 gv = *(const float4*)(lno_g + tid*4);
            const float4 bv = *(const float4*)(lno_b + tid*4);
            for (int it = 0; it < 16; ++it) {
                const int rin  = i8*16 + it;
                const int lrow = b*128 + rin;
                const int orow = b*SS + c*CHS + rin;
                const float4 v = *(const float4*)(wslot + (size_t)lrow*1024 + tid*4);
                float s1 = v.x + v.y + v.z + v.w;
                float s2 = v.x*v.x + v.y*v.y + v.z*v.z + v.w*v.w;
                #pragma unroll
                for (int off = 32; off > 0; off >>= 1) {
                    s1 += __shfl_xor(s1, off, 64);
                    s2 += __shfl_xor(s2, off, 64);
                }
                if ((tid & 63) == 0) { r1s[tid>>6] = s1; r2s[tid>>6] = s2; }
                __syncthreads();
                s1 = r1s[0] + r1s[1] + r1s[2] + r1s[3];
                s2 = r2s[0] + r2s[1] + r2s[2] + r2s[3];
                const float m   = s1 * (1.f/1024.f);
                const float var = fmaf(s2, 1.f/1024.f, -m*m);
                const float rr  = rsqrtf(var + LNEPS);
                float4 o;
                o.x = fmaf((v.x - m)*rr, gv.x, bv.x);
                o.y = fmaf((v.y - m)*rr, gv.y, bv.y);
                o.z = fmaf((v.z - m)*rr, gv.z, bv.z);
                o.w = fmaf((v.w - m)*rr, gv.w, bv.w);
                *(float4*)(out + (size_t)orow*EE + tid*4) = o;
                __syncthreads();
            }
            done_inc(&flags[81 + c]);
        }
    }
}

// ---------------------------------------------------------------------------
extern "C" void kernel_launch(void* const* d_in, const int* in_sizes, int n_in,
                              void* d_out, int out_size, void* d_ws, size_t ws_size,
                              hipStream_t stream)
{
    const float* x       = (const float*)d_in[0];
    const float* W_ez    = (const float*)d_in[1];
    const float* b_ez    = (const float*)d_in[2];
    const float* U_h     = (const float*)d_in[3];
    const float* U_z     = (const float*)d_in[4];
    const float* b_u     = (const float*)d_in[5];
    const float* outsh   = (const float*)d_in[6];
    const float* lns_g   = (const float*)d_in[7];
    const float* lns_b   = (const float*)d_in[8];
    const float* ff_ln_g = (const float*)d_in[9];
    const float* ff_ln_b = (const float*)d_in[10];
    const float* ff_W1   = (const float*)d_in[11];
    const float* ff_b1   = (const float*)d_in[12];
    const float* ff_W2   = (const float*)d_in[13];
    const float* ff_b2   = (const float*)d_in[14];
    const float* w_att   = (const float*)d_in[15];
    const float* b_att   = (const float*)d_in[16];
    const float* lno_g   = (const float*)d_in[17];
    const float* lno_b   = (const float*)d_in[18];
    float* out = (float*)d_out;

    float* ws = (float*)d_ws;
    const size_t NBIG = (size_t)BSR * HD;          // 8M floats = 32 MB
    float* bufA = ws;                              // z (fp32) — READ-ONLY in pipeline
    float* bufB = ws + NBIG;                       // xb_hi/lo -> states/gb + hln (bf16)
    float* bufC = ws + 2*NBIG;                     // WezT hi/lo -> h1 (bf16) | wsum slots
    float* ext  = ws + 3*NBIG;
    ushort* W2t   = (ushort*)ext;                  // 1M ushorts (512K floats)
    ushort* W1t   = (ushort*)(ext + 512*1024);     // 128K ushorts (64K floats)
    float* logits = ext + 512*1024 + 64*1024;      // 64K
    float* scores = logits + BSR*HH;               // 64K
    float* qv     = scores + BSR*HH;               // 1024
    float* cv     = qv + HD;                       // 8
    float* uh_d   = cv + 8;
    float* uz_d   = uh_d + HD;
    float* os_d   = uz_d + HD;
    unsigned* flags = (unsigned*)(os_d + HD);      // 128 words of sync flags
    // lifetime-disjoint aliases:
    ushort* xb_hi = (ushort*)bufB;                 // dies after gemm_mfma_hp
    ushort* xb_lo = (ushort*)bufB + NBIG;
    ushort* stb   = (ushort*)bufB;                 // scan out (16 MB, packed bf16)
    ushort* hlnb  = (ushort*)bufB + NBIG;          // headln out (16 MB)
    ushort* WezT_hi = (ushort*)bufC;               // die after gemm_mfma_hp
    ushort* WezT_lo = (ushort*)bufC + 1024*1024;
    ushort* h1b   = (ushort*)bufC;                 // h1 bf16 (first half of bufC)
    float*  wslots = bufC + 4*1024*1024;           // 8 x 2MB rotating wsum slots
    ushort* gb    = stb;                           // chunk-exact overwrite of states
                                                   // (same [bs][1024] ushort layout)

    // 0: independent prep (+ flag zeroing in block 2434)
    convx2_k<<<(BSR*EE/4)/256, 256, 0, stream>>>(x, xb_hi, xb_lo);
    prepall_k<<<2435, 256, 0, stream>>>(W_ez, WezT_hi, WezT_lo,
                                        ff_W2, W2t, ff_W1, W1t,
                                        w_att, ff_b2, b_att,
                                        U_h, U_z, outsh,
                                        qv, cv, uh_d, uz_d, os_d, flags);
    // 1: z = tanh(x @ W_ez + b_ez)   [split-bf16 MFMA, fp32-class]
    gemm_mfma_hp<<<dim3(64, 8), 256, 0, stream>>>(
        xb_hi, xb_lo, WezT_hi, WezT_lo, bufA, b_ez);
    // 2: fused producer-consumer pipeline: scan + headln + gemm_h1 +
    //    softscale + gemm_mfma + finalln, chunked over S (16 x 128 steps)
    pipeline_k<<<32 + NWORKER, 256, 0, stream>>>(
        bufA, uh_d, uz_d, b_u, lns_g, lns_b, stb,
        os_d, ff_ln_g, ff_ln_b, hlnb,
        W1t, ff_b1, qv, cv, h1b, logits,
        gb, scores, W2t, ff_b2, wslots,
        lno_g, lno_b, out, flags);
}

// Round 3
// 601.914 us; speedup vs baseline: 2.7772x; 2.7772x over previous
//
#include <hip/hip_runtime.h>
#include <hip/hip_bf16.h>
#include <math.h>

#define BB 4
#define SS 2048
#define EE 1024
#define HH 8
#define DD 128
#define BSR (BB*SS)      // 8192 rows
#define HD  (HH*DD)      // 1024
#define LNEPS 1e-5f
#define LOG2E 1.4426950408889634f

// ---- pipeline geometry ----
#define NCHUNK 16
#define CHS    128            // timesteps per chunk
#define TPC    64             // tickets per chunk: 32 B' (LN+W1) + 32 D' (scale+W2[+E])
#define NTICK  (NCHUNK*TPC)
#define NWORKER 256
#define SLOTF  (BB*CHS*1024)  // floats per wsum slot (512 rows x 1024)

// flag words: [0]=ticket  [16..31]=F_scan[c] (tgt 32)
// [32..95]=F_B[c*4+bb] (tgt 8)  [96..159]=F_D[c*4+bb] (tgt 8)
// [160..223]=F_E[c*4+bb] (tgt 1)
#define FSCAN 16
#define FB    32
#define FD    96
#define FE    160

typedef __attribute__((ext_vector_type(8))) short bf16x8;
typedef __attribute__((ext_vector_type(4))) float f32x4;

__device__ __forceinline__ ushort f2bf(float f) {
    union { float f; unsigned u; } c{f};
    unsigned r = c.u + 0x7fff + ((c.u >> 16) & 1);   // RNE
    return (ushort)(r >> 16);
}
__device__ __forceinline__ float bf2f(ushort b) {
    union { unsigned u; float f; } c{(unsigned)b << 16};
    return c.f;
}

typedef __attribute__((address_space(1))) const unsigned int GUI;
typedef __attribute__((address_space(3))) unsigned int LUI;
__device__ __forceinline__ void gl_lds16(const ushort* g, ushort* l) {
    __builtin_amdgcn_global_load_lds((GUI*)g, (LUI*)l, 16, 0, 0);
}

// ------------------------------------------------- DPP wave reduction ------
__device__ __forceinline__ float dpp_add(float x, const int ctrl) {
    int y;
    switch (ctrl) {
        case 0x111: y = __builtin_amdgcn_update_dpp(0, __float_as_int(x), 0x111, 0xf, 0xf, true); break;
        case 0x112: y = __builtin_amdgcn_update_dpp(0, __float_as_int(x), 0x112, 0xf, 0xf, true); break;
        case 0x114: y = __builtin_amdgcn_update_dpp(0, __float_as_int(x), 0x114, 0xf, 0xf, true); break;
        case 0x118: y = __builtin_amdgcn_update_dpp(0, __float_as_int(x), 0x118, 0xf, 0xf, true); break;
        case 0x142: y = __builtin_amdgcn_update_dpp(0, __float_as_int(x), 0x142, 0xf, 0xf, true); break;
        default:    y = __builtin_amdgcn_update_dpp(0, __float_as_int(x), 0x143, 0xf, 0xf, true); break;
    }
    return x + __int_as_float(y);
}

__device__ __forceinline__ float wave_sum64(float x) {
    x = dpp_add(x, 0x111);
    x = dpp_add(x, 0x112);
    x = dpp_add(x, 0x114);
    x = dpp_add(x, 0x118);
    x = dpp_add(x, 0x142);
    x = dpp_add(x, 0x143);
    return __int_as_float(__builtin_amdgcn_readlane(__float_as_int(x), 63));
}

// ------------------------------------------------ flag sync primitives -----
// Poll with RELAXED RMW (fresh value from coherence point, NO buffer_inv per
// poll — the R2 killer), then a single acquire fence on success.
__device__ __forceinline__ unsigned flag_peek(unsigned* f) {
    return __hip_atomic_fetch_add(f, 0u, __ATOMIC_RELAXED, __HIP_MEMORY_SCOPE_AGENT);
}
__device__ __forceinline__ void wait_ge(unsigned* f, unsigned tgt) {
    if (threadIdx.x == 0) {
        while (flag_peek(f) < tgt) __builtin_amdgcn_s_sleep(16);
        __builtin_amdgcn_fence(__ATOMIC_ACQUIRE, "agent");
    }
    __syncthreads();
}
// Single release fence (wbl2) + relaxed RMW. __syncthreads first drains all
// waves' vmcnt (stores at least in L2) so the fence covers the whole block.
__device__ __forceinline__ void done_inc(unsigned* f) {
    __syncthreads();
    if (threadIdx.x == 0) {
        __builtin_amdgcn_fence(__ATOMIC_RELEASE, "agent");
        __hip_atomic_fetch_add(f, 1u, __ATOMIC_RELAXED, __HIP_MEMORY_SCOPE_AGENT);
    }
}
__device__ __forceinline__ unsigned done_inc_ret(unsigned* f, unsigned* sh) {
    __syncthreads();
    if (threadIdx.x == 0) {
        __builtin_amdgcn_fence(__ATOMIC_RELEASE, "agent");
        *sh = __hip_atomic_fetch_add(f, 1u, __ATOMIC_RELAXED, __HIP_MEMORY_SCOPE_AGENT);
    }
    __syncthreads();
    return *sh;
}

// --------------------------------------- fp32 -> bf16 hi/lo split convert --
__global__ __launch_bounds__(256)
void convx2_k(const float* __restrict__ x,
              ushort* __restrict__ hi, ushort* __restrict__ lo)
{
    const size_t idx = ((size_t)blockIdx.x * 256 + threadIdx.x) * 4;
    const float4 v = *(const float4*)(x + idx);
    ushort4 oh, ol;
    oh.x = f2bf(v.x); ol.x = f2bf(v.x - bf2f(oh.x));
    oh.y = f2bf(v.y); ol.y = f2bf(v.y - bf2f(oh.y));
    oh.z = f2bf(v.z); ol.z = f2bf(v.z - bf2f(oh.z));
    oh.w = f2bf(v.w); ol.w = f2bf(v.w - bf2f(oh.w));
    *(ushort4*)(hi + idx) = oh;
    *(ushort4*)(lo + idx) = ol;
}

// ---------------------- merged weight prep (transposes + diagonals + q/c) --
__global__ __launch_bounds__(256)
void prepall_k(const float* __restrict__ W_ez,
               ushort* __restrict__ Wth, ushort* __restrict__ Wtl,
               const float* __restrict__ W2, ushort* __restrict__ W2t,
               const float* __restrict__ W1, ushort* __restrict__ W1t,
               const float* __restrict__ w_att, const float* __restrict__ b2,
               const float* __restrict__ b_att,
               const float* __restrict__ Uh, const float* __restrict__ Uz,
               const float* __restrict__ Os,
               float* __restrict__ q, float* __restrict__ c,
               float* __restrict__ uh_d, float* __restrict__ uz_d,
               float* __restrict__ os_d, unsigned* __restrict__ flags)
{
    __shared__ float tile[32][33];
    const int blk = blockIdx.x;
    if (blk == 2434) {                      // zero sync flags for the pipeline
        flags[threadIdx.x] = 0;
        return;
    }
    const int tx = threadIdx.x & 31, ty = threadIdx.x >> 5;   // ty 0..7
    if (blk < 1024) {
        const int k0 = (blk >> 5) * 32, n0 = (blk & 31) * 32;
        #pragma unroll
        for (int i = 0; i < 4; ++i)
            tile[ty + i*8][tx] = W_ez[(size_t)(k0 + ty + i*8) * 1024 + n0 + tx];
        __syncthreads();
        #pragma unroll
        for (int i = 0; i < 4; ++i) {
            const float v = tile[tx][ty + i*8];
            const ushort h = f2bf(v);
            Wth[(size_t)(n0 + ty + i*8) * 1024 + k0 + tx] = h;
            Wtl[(size_t)(n0 + ty + i*8) * 1024 + k0 + tx] = f2bf(v - bf2f(h));
        }
    } else if (blk < 2048) {
        const int b2i = blk - 1024;
        const int k0 = (b2i >> 5) * 32, n0 = (b2i & 31) * 32;
        #pragma unroll
        for (int i = 0; i < 4; ++i)
            tile[ty + i*8][tx] = W2[(size_t)(k0 + ty + i*8) * 1024 + n0 + tx];
        __syncthreads();
        #pragma unroll
        for (int i = 0; i < 4; ++i)
            W2t[(size_t)(n0 + ty + i*8) * 1024 + k0 + tx] = f2bf(tile[tx][ty + i*8]);
    } else if (blk < 2176) {
        const int idx = blk - 2048;
        const int hh = idx >> 4;
        const int k0 = (idx & 3) * 32, n0 = ((idx >> 2) & 3) * 32;
        const float* Wb = W1 + (size_t)hh * DD * DD;
        ushort*      Wtb = W1t + (size_t)hh * DD * DD;
        #pragma unroll
        for (int i = 0; i < 4; ++i)
            tile[ty + i*8][tx] = Wb[(size_t)(k0 + ty + i*8) * DD + n0 + tx];
        __syncthreads();
        #pragma unroll
        for (int i = 0; i < 4; ++i)
            Wtb[(size_t)(n0 + ty + i*8) * DD + k0 + tx] = f2bf(tile[tx][ty + i*8]);
    } else {
        const int gid  = (blk - 2176) * 256 + threadIdx.x;
        const int wave = gid >> 6, lane = gid & 63;
        if (wave < HD) {
            const float* wp = W2 + (size_t)wave * EE;
            float p = 0.f;
            for (int e = lane; e < EE; e += 64) p = fmaf(wp[e], w_att[e], p);
            #pragma unroll
            for (int off = 32; off > 0; off >>= 1) p += __shfl_xor(p, off, 64);
            if (lane == 0) {
                q[wave] = p;
                const int h = wave >> 7, d = wave & 127;
                uh_d[wave] = Uh[(size_t)h*DD*DD + (size_t)d*DD + d];
                uz_d[wave] = Uz[(size_t)h*DD*DD + (size_t)d*DD + d];
                os_d[wave] = Os[(size_t)h*DD*DD + (size_t)d*DD + d];
            }
        } else if (wave < HD + HH) {
            const int h = wave - HD;
            const float* bp = b2 + (size_t)h * EE;
            float p = 0.f;
            for (int e = lane; e < EE; e += 64) p = fmaf(bp[e], w_att[e], p);
            #pragma unroll
            for (int off = 32; off > 0; off >>= 1) p += __shfl_xor(p, off, 64);
            if (lane == 0) c[h] = p + b_att[0];
        }
    }
}

// ----------------------------------- split-bf16 MFMA GEMM (z, fp32-class) --
__global__ __launch_bounds__(256)
void gemm_mfma_hp(const ushort* __restrict__ Ah, const ushort* __restrict__ Al,
                  const ushort* __restrict__ Bh, const ushort* __restrict__ Bl,
                  float* __restrict__ C, const float* __restrict__ bias)
{
    __shared__ ushort AsmH[128*32], AsmL[128*32];
    __shared__ ushort BsmH[128*32], BsmL[128*32];
    const int t = threadIdx.x, lane = t & 63, w = t >> 6;
    const int wr = w >> 1, wc = w & 1;
    const int row0 = blockIdx.x * 128, col0 = blockIdx.y * 128;

    const int lr = lane >> 2;
    const int lc = (lane & 3) ^ (lr & 3);
    const size_t aoff0 = (size_t)(row0 +      w*16 + lr) * 1024 + lc*8;
    const size_t aoff1 = (size_t)(row0 + 64 + w*16 + lr) * 1024 + lc*8;
    const size_t boff0 = (size_t)(col0 +      w*16 + lr) * 1024 + lc*8;
    const size_t boff1 = (size_t)(col0 + 64 + w*16 + lr) * 1024 + lc*8;
    ushort* AH0 = AsmH + (     w*16) * 32;  ushort* AH1 = AsmH + (64 + w*16) * 32;
    ushort* AL0 = AsmL + (     w*16) * 32;  ushort* AL1 = AsmL + (64 + w*16) * 32;
    ushort* BH0 = BsmH + (     w*16) * 32;  ushort* BH1 = BsmH + (64 + w*16) * 32;
    ushort* BL0 = BsmL + (     w*16) * 32;  ushort* BL1 = BsmL + (64 + w*16) * 32;

    f32x4 acc[4][4];
    #pragma unroll
    for (int i = 0; i < 4; ++i)
        #pragma unroll
        for (int j = 0; j < 4; ++j) acc[i][j] = (f32x4){0.f,0.f,0.f,0.f};

    const int quad = lane >> 4;
    const int fr   = lane & 15;
    const int fchk = (quad ^ (lane & 3)) * 8;

    for (int k0 = 0; k0 < 1024; k0 += 32) {
        __syncthreads();
        gl_lds16(Ah + aoff0 + k0, AH0);
        gl_lds16(Ah + aoff1 + k0, AH1);
        gl_lds16(Bh + boff0 + k0, BH0);
        gl_lds16(Bh + boff1 + k0, BH1);
        gl_lds16(Al + aoff0 + k0, AL0);
        gl_lds16(Al + aoff1 + k0, AL1);
        gl_lds16(Bl + boff0 + k0, BL0);
        gl_lds16(Bl + boff1 + k0, BL1);
        __syncthreads();

        bf16x8 afh[4], afl[4], bfh[4], bfl[4];
        #pragma unroll
        for (int i = 0; i < 4; ++i) {
            const int ra = (wr*64 + i*16 + fr) * 32 + fchk;
            afh[i] = *(const bf16x8*)(AsmH + ra);
            afl[i] = *(const bf16x8*)(AsmL + ra);
            const int rb = (wc*64 + i*16 + fr) * 32 + fchk;
            bfh[i] = *(const bf16x8*)(BsmH + rb);
            bfl[i] = *(const bf16x8*)(BsmL + rb);
        }
        #pragma unroll
        for (int i = 0; i < 4; ++i)
            #pragma unroll
            for (int j = 0; j < 4; ++j) {
                acc[i][j] = __builtin_amdgcn_mfma_f32_16x16x32_bf16(
                    afh[i], bfl[j], acc[i][j], 0, 0, 0);
                acc[i][j] = __builtin_amdgcn_mfma_f32_16x16x32_bf16(
                    afl[i], bfh[j], acc[i][j], 0, 0, 0);
                acc[i][j] = __builtin_amdgcn_mfma_f32_16x16x32_bf16(
                    afh[i], bfh[j], acc[i][j], 0, 0, 0);
            }
    }

    float colv[4];
    #pragma unroll
    for (int tj = 0; tj < 4; ++tj)
        colv[tj] = bias[col0 + wc*64 + tj*16 + fr];
    #pragma unroll
    for (int ti = 0; ti < 4; ++ti)
        #pragma unroll
        for (int i = 0; i < 4; ++i) {
            const int row = row0 + wr*64 + ti*16 + quad*4 + i;
            #pragma unroll
            for (int tj = 0; tj < 4; ++tj) {
                const int col = col0 + wc*64 + tj*16 + fr;
                C[(size_t)row*1024 + col] = tanhf(acc[ti][tj][i] + colv[tj]);
            }
        }
}

// ===========================================================================
// Fused producer-consumer pipeline v3 (2 worker stages, cheap fences):
//   blocks [0,32)          : scan chains (b,h); release F_scan[c] per 128 steps
//   blocks [32,32+NWORKER) : persistent workers, in-order ticket queue
//     per chunk c (64 tickets):
//       r in [0,32):  B' = per-head LN (in LDS) + h1=gelu(hln@W1)+logits
//       r in [32,64): D' = softmax+scale (register-staged A) + weighted@W2;
//                     LAST finisher of (c,bb) also runs final LN -> out
// ===========================================================================
__global__ __launch_bounds__(256)
void pipeline_k(const float* __restrict__ z,
                const float* __restrict__ uh_d, const float* __restrict__ uz_d,
                const float* __restrict__ b_u,
                const float* __restrict__ lns_g, const float* __restrict__ lns_b,
                ushort* __restrict__ stb,
                const float* __restrict__ os_d,
                const float* __restrict__ ffg, const float* __restrict__ ffb,
                const ushort* __restrict__ W1t, const float* __restrict__ ff_b1,
                const float* __restrict__ qv, const float* __restrict__ cv,
                ushort* __restrict__ h1b, float* __restrict__ logits,
                const ushort* __restrict__ W2t, const float* __restrict__ ff_b2,
                float* __restrict__ wslots,
                const float* __restrict__ lno_g, const float* __restrict__ lno_b,
                float* __restrict__ out,
                unsigned* __restrict__ flags)
{
    // ------------------------------------------------------- scan role -----
    if (blockIdx.x < 32) {
        if (threadIdx.x >= 64) return;
        const int bh = blockIdx.x;
        const int b = bh >> 3, h = bh & 7;
        const int l = threadIdx.x;
        const int d0 = 2*l, d1 = d0 + 1;

        const float uhn0 = -uh_d[h*DD+d0] * LOG2E, uhn1 = -uh_d[h*DD+d1] * LOG2E;
        const float uzn0 = -uz_d[h*DD+d0] * LOG2E, uzn1 = -uz_d[h*DD+d1] * LOG2E;
        const float bun0 = -b_u [h*DD+d0] * LOG2E, bun1 = -b_u [h*DD+d1] * LOG2E;
        const float g0  = lns_g[d0], g1 = lns_g[d1];
        const float be0 = lns_b[d0], be1 = lns_b[d1];
        const float A0 = g0 * uhn0, A1 = g1 * uhn1;
        const float bunB0 = fmaf(be0, uhn0, bun0);
        const float bunB1 = fmaf(be1, uhn1, bun1);

        const float* zp = z + ((size_t)b * SS * HH + h) * DD + d0;
        unsigned* op = (unsigned*)(stb + (size_t)b * SS * HD + h * DD) + l;

        const int CH = 8;
        float2 zc[CH], zn[CH];
        float pb0[CH], pb1[CH];
        #pragma unroll
        for (int i = 0; i < CH; ++i) zc[i] = *(const float2*)(zp + (size_t)i*HD);
        #pragma unroll
        for (int i = 0; i < CH; ++i) {
            pb0[i] = fmaf(zc[i].x, uzn0, bunB0);
            pb1[i] = fmaf(zc[i].y, uzn1, bunB1);
        }

        float r_c, wp0, wp1, W0, W1, dv0, dv1;

#define PACK_STORE(HP0, HP1, OFF) do {                                       \
            const unsigned pu0 = __float_as_uint(HP0) + 0x8000u;             \
            const unsigned pu1 = __float_as_uint(HP1) + 0x8000u;             \
            op[(size_t)(OFF) * (HD/2)] =                                     \
                __builtin_amdgcn_perm(pu1, pu0, 0x07060302u);                \
        } while (0)

#define SCAN_STEP(ZX, ZY, PB0v, PB1v, ZNX, ZNY, OFF) do {                    \
            const float t0 = fmaf(r_c, W0, (PB0v));                          \
            const float t1 = fmaf(r_c, W1, (PB1v));                          \
            const float e0 = __builtin_amdgcn_exp2f(t0);                     \
            const float e1 = __builtin_amdgcn_exp2f(t1);                     \
            const float u0 = __builtin_amdgcn_rcpf(1.f + e0);                \
            const float u1 = __builtin_amdgcn_rcpf(1.f + e1);                \
            const float hn0 = fmaf(u0, dv0, (ZX));                           \
            const float hn1 = fmaf(u1, dv1, (ZY));                           \
            const float s1 = wave_sum64(hn0 + hn1);                          \
            const float s2 = wave_sum64(fmaf(hn0, hn0, hn1*hn1));            \
            const float m   = s1 * (1.f/128.f);                              \
            const float var = fmaf(s2, 1.f/128.f, -m*m);                     \
            r_c = __builtin_amdgcn_rsqf(var + LNEPS);                        \
            wp0 = hn0 - m; wp1 = hn1 - m;                                    \
            W0 = wp0 * A0; W1 = wp1 * A1;                                    \
            const float hp0 = fmaf(wp0, r_c * g0, be0);                      \
            const float hp1 = fmaf(wp1, r_c * g1, be1);                      \
            PACK_STORE(hp0, hp1, OFF);                                       \
            dv0 = hp0 - (ZNX); dv1 = hp1 - (ZNY);                            \
        } while (0)

        // ---- peel step 0 (h_prev = 0) ----
        {
            const float z0 = zc[0].x, z1 = zc[0].y;
            const float t0 = fmaf(z0, uzn0, bun0);
            const float t1 = fmaf(z1, uzn1, bun1);
            const float e0 = __builtin_amdgcn_exp2f(t0);
            const float e1 = __builtin_amdgcn_exp2f(t1);
            const float u0 = __builtin_amdgcn_rcpf(1.f + e0);
            const float u1 = __builtin_amdgcn_rcpf(1.f + e1);
            const float hn0 = fmaf(u0, -z0, z0);
            const float hn1 = fmaf(u1, -z1, z1);
            const float s1 = wave_sum64(hn0 + hn1);
            const float s2 = wave_sum64(fmaf(hn0, hn0, hn1*hn1));
            const float m   = s1 * (1.f/128.f);
            const float var = fmaf(s2, 1.f/128.f, -m*m);
            r_c = __builtin_amdgcn_rsqf(var + LNEPS);
            wp0 = hn0 - m; wp1 = hn1 - m;
            W0 = wp0 * A0; W1 = wp1 * A1;
            const float hp0 = fmaf(wp0, r_c * g0, be0);
            const float hp1 = fmaf(wp1, r_c * g1, be1);
            PACK_STORE(hp0, hp1, 0);
            dv0 = hp0 - zc[1].x; dv1 = hp1 - zc[1].y;
        }

        // ---- rest of chunk 0 (steps 1..7) ----
        #pragma unroll
        for (int i = 0; i < CH; ++i)
            zn[i] = *(const float2*)(zp + (size_t)(CH+i)*HD);
        #pragma unroll
        for (int i = 1; i < CH; ++i) {
            const float znx = (i+1 < CH) ? zc[i+1].x : zn[0].x;
            const float zny = (i+1 < CH) ? zc[i+1].y : zn[0].y;
            SCAN_STEP(zc[i].x, zc[i].y, pb0[i], pb1[i], znx, zny, i);
        }
        #pragma unroll
        for (int i = 0; i < CH; ++i) {
            zc[i] = zn[i];
            pb0[i] = fmaf(zn[i].x, uzn0, bunB0);
            pb1[i] = fmaf(zn[i].y, uzn1, bunB1);
        }

        // ---- chunks of 8 steps, flag every CHS=128 steps ----
        for (int s0 = CH; s0 < SS; s0 += CH) {
            if (s0 + CH < SS) {
                #pragma unroll
                for (int i = 0; i < CH; ++i)
                    zn[i] = *(const float2*)(zp + (size_t)(s0+CH+i)*HD);
            } else {
                #pragma unroll
                for (int i = 0; i < CH; ++i) zn[i] = make_float2(0.f, 0.f);
            }
            #pragma unroll
            for (int i = 0; i < CH; ++i) {
                const float znx = (i+1 < CH) ? zc[i+1].x : zn[0].x;
                const float zny = (i+1 < CH) ? zc[i+1].y : zn[0].y;
                SCAN_STEP(zc[i].x, zc[i].y, pb0[i], pb1[i], znx, zny, s0 + i);
            }
            #pragma unroll
            for (int i = 0; i < CH; ++i) {
                zc[i] = zn[i];
                pb0[i] = fmaf(zn[i].x, uzn0, bunB0);
                pb1[i] = fmaf(zn[i].y, uzn1, bunB1);
            }
            if ((s0 & (CHS-1)) == CHS - CH) {       // finished chunk s0>>7
                if (threadIdx.x == 0) {
                    __builtin_amdgcn_fence(__ATOMIC_RELEASE, "agent");
                    __hip_atomic_fetch_add(&flags[FSCAN + (s0 >> 7)], 1u,
                                           __ATOMIC_RELAXED, __HIP_MEMORY_SCOPE_AGENT);
                }
            }
        }
#undef SCAN_STEP
#undef PACK_STORE
        return;
    }

    // ----------------------------------------------------- worker role -----
    __shared__ ushort ApS[4*128*32];     // B': 4 A-panels (LN out); D': A stage (panel 0)
    __shared__ ushort Bsm[128*32];
    __shared__ float  sLDS[128][8];      // D': per-row softmax scores
    __shared__ float  lpart[128][2];     // B': logit partials
    __shared__ unsigned s_tk, s_old;
    const int tid = threadIdx.x;
    const int lane = tid & 63, w = tid >> 6;
    const int wr = w >> 1, wc = w & 1;
    const int lr = lane >> 2;
    const int lc = (lane & 3) ^ (lr & 3);
    const int quad = lane >> 4;
    const int fr   = lane & 15;
    const int fchk = (quad ^ (lane & 3)) * 8;

    for (;;) {
        __syncthreads();
        if (tid == 0) s_tk = __hip_atomic_fetch_add(&flags[0], 1u,
                               __ATOMIC_RELAXED, __HIP_MEMORY_SCOPE_AGENT);
        __syncthreads();
        const unsigned tk = s_tk;
        if (tk >= NTICK) return;
        const int c = (int)(tk / TPC);
        const int r = (int)(tk % TPC);

        if (r < 32) {
            // ==== stage B': per-head LN -> LDS panels, h1 GEMM, logits =====
            wait_ge(&flags[FSCAN + c], 32);
            const int bb = r >> 3, hh = r & 7;
            const int row0 = bb*SS + c*CHS;

            // ---- phase 1: LN of 128 rows (head hh) into 4 A-panels ----
            {
                const int l = lane;
                const int d0 = 2*l, d1 = d0 + 1;
                const float osd0 = os_d[hh*DD + d0], osd1 = os_d[hh*DD + d1];
                const float fg0 = ffg[hh*DD + d0], fg1 = ffg[hh*DD + d1];
                const float fb0 = ffb[hh*DD + d0], fb1 = ffb[hh*DD + d1];
                const unsigned* st_u = (const unsigned*)stb;
                const int p  = l >> 4;
                const int j  = (l >> 2) & 3;
                unsigned* ApU = (unsigned*)ApS;
                for (int it = 0; it < 32; ++it) {
                    const int rloc = it*4 + w;                 // 0..127
                    const unsigned v = st_u[(size_t)(row0 + rloc)*512 + hh*64 + l];
                    const float x0 = bf2f((ushort)(v & 0xffff)) * osd0;
                    const float x1 = bf2f((ushort)(v >> 16))    * osd1;
                    float s1 = x0 + x1;
                    float s2 = fmaf(x0, x0, x1*x1);
                    #pragma unroll
                    for (int off = 32; off > 0; off >>= 1) {
                        s1 += __shfl_xor(s1, off, 64);
                        s2 += __shfl_xor(s2, off, 64);
                    }
                    const float m   = s1 * (1.f/128.f);
                    const float var = fmaf(s2, 1.f/128.f, -m*m);
                    const float rr  = rsqrtf(var + LNEPS);
                    const float o0 = fmaf((x0 - m)*rr, fg0, fb0);
                    const float o1 = fmaf((x1 - m)*rr, fg1, fb1);
                    const unsigned pv = (unsigned)f2bf(o0) | ((unsigned)f2bf(o1) << 16);
                    const int js = j ^ (rloc & 3);
                    ApU[p*2048 + rloc*16 + js*4 + (l & 3)] = pv;
                }
            }
            __syncthreads();

            // ---- phase 2: h1 = gelu(hln @ W1[hh] + b1) + fused logits ----
            const ushort* Bg0 = W1t + (size_t)hh*DD*DD + (     w*16 + lr) * DD + lc*8;
            const ushort* Bg1 = W1t + (size_t)hh*DD*DD + (64 + w*16 + lr) * DD + lc*8;
            ushort* Bl0 = Bsm + (     w*16) * 32;
            ushort* Bl1 = Bsm + (64 + w*16) * 32;

            f32x4 acc[4][4];
            #pragma unroll
            for (int i = 0; i < 4; ++i)
                #pragma unroll
                for (int j2 = 0; j2 < 4; ++j2) acc[i][j2] = (f32x4){0.f,0.f,0.f,0.f};

            for (int k0 = 0; k0 < 128; k0 += 32) {
                __syncthreads();
                gl_lds16(Bg0 + k0, Bl0);
                gl_lds16(Bg1 + k0, Bl1);
                __syncthreads();

                const ushort* Ap = ApS + (k0 >> 5) * 4096;
                bf16x8 af[4], bf[4];
                #pragma unroll
                for (int i = 0; i < 4; ++i) {
                    af[i] = *(const bf16x8*)(Ap + (wr*64 + i*16 + fr)*32 + fchk);
                    bf[i] = *(const bf16x8*)(Bsm + (wc*64 + i*16 + fr)*32 + fchk);
                }
                #pragma unroll
                for (int i = 0; i < 4; ++i)
                    #pragma unroll
                    for (int j2 = 0; j2 < 4; ++j2)
                        acc[i][j2] = __builtin_amdgcn_mfma_f32_16x16x32_bf16(
                            af[i], bf[j2], acc[i][j2], 0, 0, 0);
            }

            float colv[4], qh[4];
            #pragma unroll
            for (int tj = 0; tj < 4; ++tj) {
                const int col = wc*64 + tj*16 + fr;
                colv[tj] = ff_b1[hh*DD + col];
                qh[tj]   = qv[hh*DD + col];
            }
            #pragma unroll
            for (int ti = 0; ti < 4; ++ti)
                #pragma unroll
                for (int i = 0; i < 4; ++i) {
                    const int row = row0 + wr*64 + ti*16 + quad*4 + i;
                    float p = 0.f;
                    #pragma unroll
                    for (int tj = 0; tj < 4; ++tj) {
                        const int col = wc*64 + tj*16 + fr;
                        float v = acc[ti][tj][i] + colv[tj];
                        v = 0.5f * v * (1.f + erff(v * 0.70710678118654752f));
                        h1b[(size_t)row*1024 + hh*DD + col] = f2bf(v);
                        p = fmaf(v, qh[tj], p);
                    }
                    p = dpp_add(p, 0x111);
                    p = dpp_add(p, 0x112);
                    p = dpp_add(p, 0x114);
                    p = dpp_add(p, 0x118);
                    if (fr == 15)
                        lpart[wr*64 + ti*16 + quad*4 + i][wc] = p;
                }
            __syncthreads();
            if (tid < 128)
                logits[(size_t)(row0 + tid)*HH + hh] = lpart[tid][0] + lpart[tid][1] + cv[hh];
            done_inc(&flags[FB + c*4 + bb]);
        } else {
            // ==== stage D': softmax+scale staged A, weighted @ W2 [+ E] ====
            const int sub = r - 32;
            const int bb = sub >> 3, cb = sub & 7;
            wait_ge(&flags[FB + c*4 + bb], 8);
            if (c >= 8) wait_ge(&flags[FE + (c-8)*4 + bb], 1);   // slot free
            const int row0 = bb*SS + c*CHS, col0 = cb*128;
            float* wslot = wslots + (size_t)(c & 7) * SLOTF;

            // ---- phase 0: per-row softmax over heads -> sLDS ----
            if (tid < 128) {
                const float4 l03 = *(const float4*)(logits + (size_t)(row0 + tid)*8);
                const float4 l47 = *(const float4*)(logits + (size_t)(row0 + tid)*8 + 4);
                float lv[8] = {l03.x,l03.y,l03.z,l03.w,l47.x,l47.y,l47.z,l47.w};
                float mx = -1e30f;
                #pragma unroll
                for (int i = 0; i < 8; ++i) mx = fmaxf(mx, lv[i]);
                float den = 0.f;
                #pragma unroll
                for (int i = 0; i < 8; ++i) den += __expf(lv[i] - mx);
                const float rden = 1.f / den;
                #pragma unroll
                for (int i = 0; i < 8; ++i) sLDS[tid][i] = __expf(lv[i] - mx) * rden;
            }
            __syncthreads();

            const ushort* Bg0 = W2t + (size_t)(col0 +      w*16 + lr) * 1024 + lc*8;
            const ushort* Bg1 = W2t + (size_t)(col0 + 64 + w*16 + lr) * 1024 + lc*8;
            ushort* Bl0 = Bsm + (     w*16) * 32;
            ushort* Bl1 = Bsm + (64 + w*16) * 32;
            const int rl0 = w*16 + lr, rl1 = 64 + w*16 + lr;

            f32x4 acc[4][4];
            #pragma unroll
            for (int i = 0; i < 4; ++i)
                #pragma unroll
                for (int j2 = 0; j2 < 4; ++j2) acc[i][j2] = (f32x4){0.f,0.f,0.f,0.f};

            for (int k0 = 0; k0 < 1024; k0 += 32) {
                __syncthreads();
                // A: register-staged scale (h1 * score), layout == gl_lds16's
                {
                    const int kk = k0 + lc*8;
                    const int hidx = kk >> 7;
                    bf16x8 a0 = *(const bf16x8*)(h1b + (size_t)(row0 + rl0)*1024 + kk);
                    bf16x8 a1 = *(const bf16x8*)(h1b + (size_t)(row0 + rl1)*1024 + kk);
                    const float sc0 = sLDS[rl0][hidx];
                    const float sc1 = sLDS[rl1][hidx];
                    bf16x8 w0, w1;
                    #pragma unroll
                    for (int e = 0; e < 8; ++e) {
                        w0[e] = (short)f2bf(bf2f((ushort)a0[e]) * sc0);
                        w1[e] = (short)f2bf(bf2f((ushort)a1[e]) * sc1);
                    }
                    *(bf16x8*)(ApS + (     w*16)*32 + lane*8) = w0;
                    *(bf16x8*)(ApS + (64 + w*16)*32 + lane*8) = w1;
                }
                gl_lds16(Bg0 + k0, Bl0);
                gl_lds16(Bg1 + k0, Bl1);
                __syncthreads();

                bf16x8 af[4], bf[4];
                #pragma unroll
                for (int i = 0; i < 4; ++i) {
                    af[i] = *(const bf16x8*)(ApS + (wr*64 + i*16 + fr)*32 + fchk);
                    bf[i] = *(const bf16x8*)(Bsm + (wc*64 + i*16 + fr)*32 + fchk);
                }
                #pragma unroll
                for (int i = 0; i < 4; ++i)
                    #pragma unroll
                    for (int j2 = 0; j2 < 4; ++j2)
                        acc[i][j2] = __builtin_amdgcn_mfma_f32_16x16x32_bf16(
                            af[i], bf[j2], acc[i][j2], 0, 0, 0);
            }

            float b2v[4][HH];
            #pragma unroll
            for (int tj = 0; tj < 4; ++tj) {
                const int col = col0 + wc*64 + tj*16 + fr;
                #pragma unroll
                for (int h = 0; h < HH; ++h) b2v[tj][h] = ff_b2[(size_t)h*EE + col];
            }
            #pragma unroll
            for (int ti = 0; ti < 4; ++ti)
                #pragma unroll
                for (int i = 0; i < 4; ++i) {
                    const int lrow = wr*64 + ti*16 + quad*4 + i;       // 0..127
                    float sc[HH];
                    #pragma unroll
                    for (int h = 0; h < HH; ++h) sc[h] = sLDS[lrow][h];
                    #pragma unroll
                    for (int tj = 0; tj < 4; ++tj) {
                        const int col = col0 + wc*64 + tj*16 + fr;
                        float bbv = 0.f;
                        #pragma unroll
                        for (int h = 0; h < HH; ++h) bbv = fmaf(sc[h], b2v[tj][h], bbv);
                        wslot[(size_t)(bb*128 + lrow)*1024 + col] = acc[ti][tj][i] + bbv;
                    }
                }

            const unsigned old = done_inc_ret(&flags[FD + c*4 + bb], &s_old);
            if (old == 7) {
                // ---- last finisher: final LayerNorm for (c,bb) -> out ----
                if (tid == 0) __builtin_amdgcn_fence(__ATOMIC_ACQUIRE, "agent");
                __syncthreads();
                const float* wsE = wslots + (size_t)(c & 7) * SLOTF
                                 + (size_t)bb * 128 * 1024;
                float4 gvq[4], bvq[4];
                #pragma unroll
                for (int q4 = 0; q4 < 4; ++q4) {
                    gvq[q4] = *(const float4*)(lno_g + lane*4 + q4*256);
                    bvq[q4] = *(const float4*)(lno_b + lane*4 + q4*256);
                }
                for (int it = 0; it < 32; ++it) {
                    const int rloc = it*4 + w;
                    const float* wp = wsE + (size_t)rloc*1024;
                    float4 vq[4];
                    float s1 = 0.f, s2 = 0.f;
                    #pragma unroll
                    for (int q4 = 0; q4 < 4; ++q4) {
                        vq[q4] = *(const float4*)(wp + lane*4 + q4*256);
                        s1 += vq[q4].x + vq[q4].y + vq[q4].z + vq[q4].w;
                        s2 += vq[q4].x*vq[q4].x + vq[q4].y*vq[q4].y
                            + vq[q4].z*vq[q4].z + vq[q4].w*vq[q4].w;
                    }
                    #pragma unroll
                    for (int off = 32; off > 0; off >>= 1) {
                        s1 += __shfl_xor(s1, off, 64);
                        s2 += __shfl_xor(s2, off, 64);
                    }
                    const float m   = s1 * (1.f/1024.f);
                    const float var = fmaf(s2, 1.f/1024.f, -m*m);
                    const float rr  = rsqrtf(var + LNEPS);
                    float* op = out + (size_t)(row0 + rloc)*1024;
                    #pragma unroll
                    for (int q4 = 0; q4 < 4; ++q4) {
                        float4 o;
                        o.x = fmaf((vq[q4].x - m)*rr, gvq[q4].x, bvq[q4].x);
                        o.y = fmaf((vq[q4].y - m)*rr, gvq[q4].y, bvq[q4].y);
                        o.z = fmaf((vq[q4].z - m)*rr, gvq[q4].z, bvq[q4].z);
                        o.w = fmaf((vq[q4].w - m)*rr, gvq[q4].w, bvq[q4].w);
                        *(float4*)(op + lane*4 + q4*256) = o;
                    }
                }
                done_inc(&flags[FE + c*4 + bb]);
            }
        }
    }
}

// ---------------------------------------------------------------------------
extern "C" void kernel_launch(void* const* d_in, const int* in_sizes, int n_in,
                              void* d_out, int out_size, void* d_ws, size_t ws_size,
                              hipStream_t stream)
{
    const float* x       = (const float*)d_in[0];
    const float* W_ez    = (const float*)d_in[1];
    const float* b_ez    = (const float*)d_in[2];
    const float* U_h     = (const float*)d_in[3];
    const float* U_z     = (const float*)d_in[4];
    const float* b_u     = (const float*)d_in[5];
    const float* outsh   = (const float*)d_in[6];
    const float* lns_g   = (const float*)d_in[7];
    const float* lns_b   = (const float*)d_in[8];
    const float* ff_ln_g = (const float*)d_in[9];
    const float* ff_ln_b = (const float*)d_in[10];
    const float* ff_W1   = (const float*)d_in[11];
    const float* ff_b1   = (const float*)d_in[12];
    const float* ff_W2   = (const float*)d_in[13];
    const float* ff_b2   = (const float*)d_in[14];
    const float* w_att   = (const float*)d_in[15];
    const float* b_att   = (const float*)d_in[16];
    const float* lno_g   = (const float*)d_in[17];
    const float* lno_b   = (const float*)d_in[18];
    float* out = (float*)d_out;

    float* ws = (float*)d_ws;
    const size_t NBIG = (size_t)BSR * HD;          // 8M floats = 32 MB
    float* bufA = ws;                              // z (fp32) — READ-ONLY in pipeline
    float* bufB = ws + NBIG;                       // xb_hi/lo -> states (bf16)
    float* bufC = ws + 2*NBIG;                     // WezT hi/lo -> h1 (bf16) | wsum slots
    float* ext  = ws + 3*NBIG;
    ushort* W2t   = (ushort*)ext;                  // 1M ushorts (512K floats)
    ushort* W1t   = (ushort*)(ext + 512*1024);     // 128K ushorts (64K floats)
    float* logits = ext + 512*1024 + 64*1024;      // 64K
    float* qv     = logits + BSR*HH;               // 1024
    float* cv     = qv + HD;                       // 8
    float* uh_d   = cv + 8;
    float* uz_d   = uh_d + HD;
    float* os_d   = uz_d + HD;
    unsigned* flags = (unsigned*)(os_d + HD);      // 256 words of sync flags
    // lifetime-disjoint aliases:
    ushort* xb_hi = (ushort*)bufB;                 // dies after gemm_mfma_hp
    ushort* xb_lo = (ushort*)bufB + NBIG;
    ushort* stb   = (ushort*)bufB;                 // scan out (16 MB, packed bf16)
    ushort* WezT_hi = (ushort*)bufC;               // die after gemm_mfma_hp
    ushort* WezT_lo = (ushort*)bufC + 1024*1024;
    ushort* h1b   = (ushort*)bufC;                 // h1 bf16 (first half of bufC)
    float*  wslots = bufC + 4*1024*1024;           // 8 x 2MB rotating wsum slots

    // 0: independent prep (+ flag zeroing in block 2434)
    convx2_k<<<(BSR*EE/4)/256, 256, 0, stream>>>(x, xb_hi, xb_lo);
    prepall_k<<<2435, 256, 0, stream>>>(W_ez, WezT_hi, WezT_lo,
                                        ff_W2, W2t, ff_W1, W1t,
                                        w_att, ff_b2, b_att,
                                        U_h, U_z, outsh,
                                        qv, cv, uh_d, uz_d, os_d, flags);
    // 1: z = tanh(x @ W_ez + b_ez)   [split-bf16 MFMA, fp32-class]
    gemm_mfma_hp<<<dim3(64, 8), 256, 0, stream>>>(
        xb_hi, xb_lo, WezT_hi, WezT_lo, bufA, b_ez);
    // 2: fused producer-consumer pipeline v3
    pipeline_k<<<32 + NWORKER, 256, 0, stream>>>(
        bufA, uh_d, uz_d, b_u, lns_g, lns_b, stb,
        os_d, ff_ln_g, ff_ln_b,
        W1t, ff_b1, qv, cv, h1b, logits,
        W2t, ff_b2, wslots,
        lno_g, lno_b, out, flags);
}